// Round 1
// baseline (188.067 us; speedup 1.0000x reference)
//
#include <hip/hip_runtime.h>
#include <hip/hip_bf16.h>

constexpr int Bb  = 4;
constexpr int Nn  = 1024;
constexpr int Fin = 256;
constexpr int Cc  = 256;   // H*HID
constexpr int Hh  = 8;
constexpr int Hid = 32;
constexpr float Alpha = 0.2f;

// ---------------- K1: s = h @ W  (M=4096, K=256, N=256) ----------------
constexpr int BM = 64, BN = 64, BK = 32, ASTR = 36; // ASTR: 16B-aligned pad, breaks bank conflicts

__global__ __launch_bounds__(256) void k_gemm(const float* __restrict__ hin,
                                              const float* __restrict__ W,
                                              float* __restrict__ s) {
    __shared__ float As[BM * ASTR];
    __shared__ float Bs[BK * BN];
    const int t = threadIdx.x;
    const int row0 = blockIdx.y * BM;
    const int col0 = blockIdx.x * BN;
    const int tx = t & 15, ty = t >> 4;
    float acc[4][4] = {};
    for (int k0 = 0; k0 < Fin; k0 += BK) {
        #pragma unroll
        for (int v = t; v < BM * BK / 4; v += 256) {
            int r = v >> 3, k4 = v & 7;
            float4 av = *reinterpret_cast<const float4*>(
                &hin[(size_t)(row0 + r) * Fin + k0 + k4 * 4]);
            *reinterpret_cast<float4*>(&As[r * ASTR + k4 * 4]) = av;
        }
        #pragma unroll
        for (int v = t; v < BK * BN / 4; v += 256) {
            int kk = v >> 4, c4 = v & 15;
            *reinterpret_cast<float4*>(&Bs[kk * BN + c4 * 4]) =
                *reinterpret_cast<const float4*>(
                    &W[(size_t)(k0 + kk) * Cc + col0 + c4 * 4]);
        }
        __syncthreads();
        #pragma unroll
        for (int kk = 0; kk < BK; ++kk) {
            float ar[4];
            #pragma unroll
            for (int i = 0; i < 4; ++i) ar[i] = As[(ty * 4 + i) * ASTR + kk];
            float4 bv = *reinterpret_cast<const float4*>(&Bs[kk * BN + tx * 4]);
            #pragma unroll
            for (int i = 0; i < 4; ++i) {
                acc[i][0] = fmaf(ar[i], bv.x, acc[i][0]);
                acc[i][1] = fmaf(ar[i], bv.y, acc[i][1]);
                acc[i][2] = fmaf(ar[i], bv.z, acc[i][2]);
                acc[i][3] = fmaf(ar[i], bv.w, acc[i][3]);
            }
        }
        __syncthreads();
    }
    #pragma unroll
    for (int i = 0; i < 4; ++i) {
        float4 o = make_float4(acc[i][0], acc[i][1], acc[i][2], acc[i][3]);
        *reinterpret_cast<float4*>(
            &s[(size_t)(row0 + ty * 4 + i) * Cc + col0 + tx * 4]) = o;
    }
}

// ---------------- K2: e_i/e_j = s . a_left / a_right ----------------
__global__ void k_edge(const float* __restrict__ s, const float* __restrict__ av,
                       float* __restrict__ ei, float* __restrict__ ej) {
    const int idx = blockIdx.x * 256 + threadIdx.x;   // (b*N+n)*H + h
    const int hh = idx & 7;
    const int bn = idx >> 3;
    const float* sp = &s[(size_t)bn * Cc + hh * Hid];
    float si = 0.f, sj = 0.f;
    #pragma unroll
    for (int f4 = 0; f4 < 8; ++f4) {
        float4 sv = *reinterpret_cast<const float4*>(&sp[f4 * 4]);
        float4 al = *reinterpret_cast<const float4*>(&av[f4 * 4]);
        float4 ar = *reinterpret_cast<const float4*>(&av[Hid + f4 * 4]);
        si += sv.x * al.x + sv.y * al.y + sv.z * al.z + sv.w * al.w;
        sj += sv.x * ar.x + sv.y * ar.y + sv.z * ar.z + sv.w * ar.w;
    }
    ei[idx] = si;
    ej[idx] = sj;
}

// ---------------- K3: column sums Z[b,j,h] (partial over i-chunks) ----------------
// No max-subtraction needed: |e_i+e_j| <= ~2, exp bounded, ratio identical to softmax.
__global__ __launch_bounds__(256) void k_colsum(const float* __restrict__ ei,
                                                const float* __restrict__ ej,
                                                const int* __restrict__ adj,
                                                float* __restrict__ Zp) {
    const int chunk = blockIdx.x;          // 4 i-chunks of 256 rows
    const int j0 = blockIdx.y * 64;        // 16 column tiles
    const int b = blockIdx.z;              // 4 batches
    const int i0 = chunk * 256;
    const int t = threadIdx.x;
    const int jj = t & 63;
    const int g = t >> 6;
    __shared__ float ei_s[256 * Hh];
    __shared__ float red[4 * 64 * Hh];
    for (int v = t; v < 256 * Hh; v += 256)
        ei_s[v] = ei[((size_t)b * Nn + i0) * Hh + v];
    float ejr[Hh];
    #pragma unroll
    for (int hh = 0; hh < Hh; ++hh)
        ejr[hh] = ej[((size_t)b * Nn + j0 + jj) * Hh + hh];
    __syncthreads();
    float z[Hh] = {};
    const int* ap = &adj[((size_t)b * Nn + i0 + g * 64) * Nn + j0 + jj];
    for (int it = 0; it < 64; ++it) {
        int a = ap[(size_t)it * Nn];       // coalesced 64-wide row read
        if (a) {
            const float* ep = &ei_s[(g * 64 + it) * Hh];
            #pragma unroll
            for (int hh = 0; hh < Hh; ++hh) {
                float x = ep[hh] + ejr[hh];
                x = fmaxf(x, Alpha * x);   // leaky relu
                z[hh] += __expf(x);
            }
        }
    }
    #pragma unroll
    for (int hh = 0; hh < Hh; ++hh)
        red[(g * 64 + jj) * Hh + hh] = z[hh];
    __syncthreads();
    for (int v = t; v < 64 * Hh; v += 256) {
        float sum = red[v] + red[512 + v] + red[1024 + v] + red[1536 + v];
        Zp[(size_t)chunk * (Bb * Nn * Hh) + ((size_t)b * Nn + j0) * Hh + v] = sum;
    }
}

// ---------------- K4: combine partials + reciprocal ----------------
__global__ void k_rcpz(const float* __restrict__ Zp, float* __restrict__ rz) {
    const int idx = blockIdx.x * 256 + threadIdx.x;   // 32768
    constexpr int S = Bb * Nn * Hh;
    float sum = Zp[idx] + Zp[S + idx] + Zp[2 * S + idx] + Zp[3 * S + idx];
    rz[idx] = 1.0f / sum;
}

// ---------------- K5: out[b,i,h*32+f] = bias + sum_j w[i,j]*s[j,h*32+f] ----------------
// Flat grid of 512 blocks, decoded so the 8 head-siblings that share an adj
// row-slab have equal bid%8 -> same XCD -> adj re-reads hit that XCD's L2.
__global__ __launch_bounds__(256) void k_agg(const float* __restrict__ s,
                                             const float* __restrict__ ei,
                                             const float* __restrict__ ej,
                                             const float* __restrict__ rz,
                                             const int* __restrict__ adj,
                                             const float* __restrict__ bias,
                                             float* __restrict__ out) {
    const int bid = blockIdx.x;
    const int h = bid >> 6;               // 8 heads, slowest -> siblings 64 apart
    const int rest = bid & 63;
    const int b = rest >> 4;
    const int i0 = (rest & 15) * 64;
    const int t = threadIdx.x;
    constexpr int WSTR = 68;              // pad: write conflict 32-way -> 4-way, keeps 16B align
    __shared__ float ei_s[64];
    __shared__ float w_s[32 * WSTR];      // [j'][i]
    __shared__ float s_s[32 * 32];        // [j'][f]
    if (t < 64) ei_s[t] = ei[((size_t)b * Nn + i0 + t) * Hh + h];
    __syncthreads();

    const int f = t & 31;
    const int rg = t >> 5;                // row group: rows rg*8 .. rg*8+7
    float acc[8] = {};

    for (int jb = 0; jb < Nn; jb += 32) {
        // stage s tile (32 j x 32 f)
        {
            int j_ = t >> 3, f4 = t & 7;
            *reinterpret_cast<float4*>(&s_s[j_ * 32 + f4 * 4]) =
                *reinterpret_cast<const float4*>(
                    &s[((size_t)b * Nn + jb + j_) * Cc + h * Hid + f4 * 4]);
        }
        // w phase: 64 i x 32 j attention weights, 8 per thread
        const int jw = f;                  // column within tile
        float ejv = ej[((size_t)b * Nn + jb + jw) * Hh + h];
        float rzv = rz[((size_t)b * Nn + jb + jw) * Hh + h];
        const int* ap = &adj[((size_t)b * Nn + i0 + rg * 8) * Nn + jb + jw];
        #pragma unroll
        for (int k = 0; k < 8; ++k) {
            int a = ap[(size_t)k * Nn];    // coalesced 32-wide
            float x = ei_s[rg * 8 + k] + ejv;
            x = fmaxf(x, Alpha * x);
            float w = a ? __expf(x) * rzv : 0.0f;
            w_s[jw * WSTR + rg * 8 + k] = w;
        }
        __syncthreads();
        // fma phase: each thread 8 rows x 1 channel
        #pragma unroll
        for (int j = 0; j < 32; ++j) {
            float sv = s_s[j * 32 + f];
            const float* wp = &w_s[j * WSTR + rg * 8];
            float4 w0 = *reinterpret_cast<const float4*>(wp);       // broadcast reads
            float4 w1 = *reinterpret_cast<const float4*>(wp + 4);
            acc[0] = fmaf(w0.x, sv, acc[0]);
            acc[1] = fmaf(w0.y, sv, acc[1]);
            acc[2] = fmaf(w0.z, sv, acc[2]);
            acc[3] = fmaf(w0.w, sv, acc[3]);
            acc[4] = fmaf(w1.x, sv, acc[4]);
            acc[5] = fmaf(w1.y, sv, acc[5]);
            acc[6] = fmaf(w1.z, sv, acc[6]);
            acc[7] = fmaf(w1.w, sv, acc[7]);
        }
        __syncthreads();
    }
    const float bv = bias[h * Hid + f];
    #pragma unroll
    for (int k = 0; k < 8; ++k)
        out[((size_t)b * Nn + i0 + rg * 8 + k) * Cc + h * Hid + f] = acc[k] + bv;
}

extern "C" void kernel_launch(void* const* d_in, const int* in_sizes, int n_in,
                              void* d_out, int out_size, void* d_ws, size_t ws_size,
                              hipStream_t stream) {
    const float* hin  = (const float*)d_in[0];
    const int*   adj  = (const int*)d_in[1];
    const float* W    = (const float*)d_in[2];
    const float* a    = (const float*)d_in[3];
    const float* bias = (const float*)d_in[4];
    float* out = (float*)d_out;
    float* ws  = (float*)d_ws;

    float* s   = ws;                      // 1,048,576 f32 (4 MB)
    float* ei  = ws + 1048576;            // 32,768
    float* ej  = ws + 1081344;            // 32,768
    float* Zp  = ws + 1114112;            // 4 x 32,768 partials
    float* rz  = ws + 1245184;            // 32,768

    k_gemm  <<<dim3(Cc / BN, (Bb * Nn) / BM), 256, 0, stream>>>(hin, W, s);
    k_edge  <<<dim3((Bb * Nn * Hh) / 256),    256, 0, stream>>>(s, a, ei, ej);
    k_colsum<<<dim3(4, 16, 4),                256, 0, stream>>>(ei, ej, adj, Zp);
    k_rcpz  <<<dim3((Bb * Nn * Hh) / 256),    256, 0, stream>>>(Zp, rz);
    k_agg   <<<dim3(512),                     256, 0, stream>>>(s, ei, ej, rz, adj, bias, out);
}